// Round 6
// baseline (106.674 us; speedup 1.0000x reference)
//
#include <hip/hip_runtime.h>

// EWMA scan y_t = (1-a)*y_{t-1} + a*x_t, y_{-1} = first_offset.
// 3-kernel chunked scan, L3-aware:
//   K1: nt-load data (read-once, don't pollute L3), compute zero-init local
//       scan, write UNCORRECTED y_local straight to out (L3-resident dirty),
//       publish per-chunk aggregates.
//   K2: inter-chunk scan (one wave per column, Kogge-Stone over 64 lanes).
//   K3: read out (L3 hit), add decay^(i+1)*carry, write back in place.
//       Single final HBM writeback; data is never re-read.

#define LT   32768
#define DC   1024
#define TCH  32               // timesteps per chunk
#define CCH  (LT / TCH)       // 1024 chunks
#define TPB  256
#define D4   (DC / 4)         // 256 float4 per row

typedef float nf4 __attribute__((ext_vector_type(4)));

__global__ void ewma_k1(const nf4* __restrict__ data4,
                        nf4* __restrict__ out4,
                        nf4* __restrict__ zend4,
                        const float* __restrict__ alpha_p) {
    const float alpha = alpha_p[0];
    const float decay = 1.0f - alpha;
    const int tid = threadIdx.x;    // float4 column group
    const int c = blockIdx.x;       // chunk index
    const nf4* p = data4 + (size_t)c * TCH * D4 + tid;
    nf4* o = out4 + (size_t)c * TCH * D4 + tid;
    float z0 = 0.f, z1 = 0.f, z2 = 0.f, z3 = 0.f;
#pragma unroll 8
    for (int i = 0; i < TCH; ++i) {
        nf4 x = __builtin_nontemporal_load(&p[(size_t)i * D4]);
        z0 = fmaf(decay, z0, alpha * x.x);
        z1 = fmaf(decay, z1, alpha * x.y);
        z2 = fmaf(decay, z2, alpha * x.z);
        z3 = fmaf(decay, z3, alpha * x.w);
        nf4 zv; zv.x = z0; zv.y = z1; zv.z = z2; zv.w = z3;
        o[(size_t)i * D4] = zv;           // uncorrected local scan
    }
    nf4 ze; ze.x = z0; ze.y = z1; ze.z = z2; ze.w = z3;
    zend4[c * D4 + tid] = ze;
}

// One wave per column d. Lane l owns chunks [l*CPL, (l+1)*CPL).
// Inter-chunk recurrence: S_c = r * S_{c-1} + e_c, r = decay^TCH.
__global__ void ewma_k2(const float* __restrict__ zend,
                        const float* __restrict__ first,
                        float* __restrict__ carry,
                        const float* __restrict__ alpha_p) {
    const float alpha = alpha_p[0];
    const float decay = 1.0f - alpha;
    float r = decay;                 // decay^TCH via 5 squarings (TCH=32)
    r *= r; r *= r; r *= r; r *= r; r *= r;

    const int lane = threadIdx.x & 63;
    const int d = (blockIdx.x * blockDim.x + threadIdx.x) >> 6;  // column
    constexpr int CPL = CCH / 64;   // 16 chunks per lane

    float e[CPL];
#pragma unroll
    for (int j = 0; j < CPL; ++j)
        e[j] = zend[(lane * CPL + j) * DC + d];

    // lane-local aggregate with ratio r, zero init
    float A = 0.f;
#pragma unroll
    for (int j = 0; j < CPL; ++j) A = fmaf(r, A, e[j]);

    // q = r^CPL, CPL=16
    float q = r;
    q *= q; q *= q; q *= q; q *= q;

    // Kogge-Stone inclusive scan across 64 lanes
    float y = A;
    float p = q;
#pragma unroll
    for (int o = 1; o < 64; o <<= 1) {
        float prev = __shfl_up(y, o, 64);
        if (lane >= o) y = fmaf(p, prev, y);
        p = p * p;
    }
    float excl = __shfl_up(y, 1, 64);
    if (lane == 0) excl = 0.f;

    // decayed first_offset contribution: q^lane
    float qpow = 1.f;
    {
        float base = q;
        int e2 = lane;
        while (e2) { if (e2 & 1) qpow *= base; base *= base; e2 >>= 1; }
    }
    float S = fmaf(qpow, first[d], excl);  // carry entering lane's first chunk

#pragma unroll
    for (int j = 0; j < CPL; ++j) {
        const int c = lane * CPL + j;
        carry[c * DC + d] = S;             // carry-in for chunk c
        S = fmaf(r, S, e[j]);
    }
}

__global__ void ewma_k3(nf4* __restrict__ out4,
                        const nf4* __restrict__ carry4,
                        nf4* __restrict__ out_last4,
                        const float* __restrict__ alpha_p) {
    const float alpha = alpha_p[0];
    const float decay = 1.0f - alpha;
    const int tid = threadIdx.x;
    const int c = blockIdx.x;
    const nf4 cin = carry4[c * D4 + tid];
    nf4* o = out4 + (size_t)c * TCH * D4 + tid;
    float pw = 1.f;
    nf4 yv;
#pragma unroll 8
    for (int i = 0; i < TCH; ++i) {
        nf4 v = o[(size_t)i * D4];        // L3-resident (written by K1)
        pw *= decay;
        yv.x = fmaf(pw, cin.x, v.x);
        yv.y = fmaf(pw, cin.y, v.y);
        yv.z = fmaf(pw, cin.z, v.z);
        yv.w = fmaf(pw, cin.w, v.w);
        o[(size_t)i * D4] = yv;
    }
    if (c == CCH - 1)
        out_last4[tid] = yv;              // last-row output
}

extern "C" void kernel_launch(void* const* d_in, const int* in_sizes, int n_in,
                              void* d_out, int out_size, void* d_ws, size_t ws_size,
                              hipStream_t stream) {
    const float* data    = (const float*)d_in[0];
    const float* first   = (const float*)d_in[1];
    const float* alpha_p = (const float*)d_in[2];
    float* out = (float*)d_out;

    float* zend  = (float*)d_ws;              // CCH*DC floats = 4 MB
    float* carry = zend + (size_t)CCH * DC;   // CCH*DC floats = 4 MB

    ewma_k1<<<CCH, TPB, 0, stream>>>(
        (const nf4*)data, (nf4*)out, (nf4*)zend, alpha_p);

    ewma_k2<<<DC / (TPB / 64), TPB, 0, stream>>>(
        zend, first, carry, alpha_p);

    ewma_k3<<<CCH, TPB, 0, stream>>>(
        (nf4*)out, (const nf4*)carry,
        (nf4*)(out + (size_t)LT * DC), alpha_p);
}

// Round 7
// 96.321 us; speedup vs baseline: 1.1075x; 1.1075x over previous
//
#include <hip/hip_runtime.h>

// EWMA scan y_t = (1-a)*y_{t-1} + a*x_t, y_{-1} = first_offset.
// 3-phase chunked scan (R1 structure, plain loads/stores — nt hints measured
// harmful on gfx950: R4 nt-store +10us, R6 nt-load +32us).
// Only change vs R1: TCH 64->16 => 2048 blocks (8/CU) in the two streaming
// phases for latency hiding.
//   phase1: per-chunk zero-init local scan end values (aggregates)
//   phase2: inter-chunk scan, one wave per column (Kogge-Stone over lanes)
//   phase3: recompute local scan (data re-read mostly L3-resident), add
//           decayed carry, store out.

#define LT   32768
#define DC   1024
#define TCH  16               // timesteps per chunk
#define CCH  (LT / TCH)       // 2048 chunks
#define TPB  256
#define D4   (DC / 4)         // 256 float4 per row

typedef float nf4 __attribute__((ext_vector_type(4)));

__global__ __launch_bounds__(TPB, 8)
void ewma_phase1(const nf4* __restrict__ data4,
                 nf4* __restrict__ zend4,
                 const float* __restrict__ alpha_p) {
    const float alpha = alpha_p[0];
    const float decay = 1.0f - alpha;
    const int tid = threadIdx.x;    // float4 column group
    const int c = blockIdx.x;       // chunk index
    const nf4* p = data4 + (size_t)c * TCH * D4 + tid;
    float z0 = 0.f, z1 = 0.f, z2 = 0.f, z3 = 0.f;
#pragma unroll
    for (int i = 0; i < TCH; ++i) {
        nf4 x = p[(size_t)i * D4];
        z0 = fmaf(decay, z0, alpha * x.x);
        z1 = fmaf(decay, z1, alpha * x.y);
        z2 = fmaf(decay, z2, alpha * x.z);
        z3 = fmaf(decay, z3, alpha * x.w);
    }
    nf4 zv; zv.x = z0; zv.y = z1; zv.z = z2; zv.w = z3;
    zend4[c * D4 + tid] = zv;
}

// One wave per column d. Lane l owns chunks [l*CPL, (l+1)*CPL).
// Inter-chunk recurrence: S_c = r * S_{c-1} + e_c, r = decay^TCH.
__global__ __launch_bounds__(TPB, 8)
void ewma_phase2(const float* __restrict__ zend,
                 const float* __restrict__ first,
                 float* __restrict__ carry,
                 const float* __restrict__ alpha_p) {
    const float alpha = alpha_p[0];
    const float decay = 1.0f - alpha;
    float r = decay;                 // decay^TCH via 4 squarings (TCH=16)
    r *= r; r *= r; r *= r; r *= r;

    const int lane = threadIdx.x & 63;
    const int d = (blockIdx.x * blockDim.x + threadIdx.x) >> 6;  // column
    constexpr int CPL = CCH / 64;   // 32 chunks per lane

    float e[CPL];
#pragma unroll
    for (int j = 0; j < CPL; ++j)
        e[j] = zend[(lane * CPL + j) * DC + d];

    // lane-local aggregate with ratio r, zero init
    float A = 0.f;
#pragma unroll
    for (int j = 0; j < CPL; ++j) A = fmaf(r, A, e[j]);

    // q = r^CPL, CPL=32
    float q = r;
    q *= q; q *= q; q *= q; q *= q; q *= q;

    // Kogge-Stone inclusive scan across 64 lanes
    float y = A;
    float p = q;
#pragma unroll
    for (int o = 1; o < 64; o <<= 1) {
        float prev = __shfl_up(y, o, 64);
        if (lane >= o) y = fmaf(p, prev, y);
        p = p * p;
    }
    float excl = __shfl_up(y, 1, 64);
    if (lane == 0) excl = 0.f;

    // decayed first_offset contribution: q^lane
    float qpow = 1.f;
    {
        float base = q;
        int e2 = lane;
        while (e2) { if (e2 & 1) qpow *= base; base *= base; e2 >>= 1; }
    }
    float S = fmaf(qpow, first[d], excl);  // carry entering lane's first chunk

#pragma unroll
    for (int j = 0; j < CPL; ++j) {
        const int c = lane * CPL + j;
        carry[c * DC + d] = S;             // carry-in for chunk c
        S = fmaf(r, S, e[j]);
    }
}

__global__ __launch_bounds__(TPB, 8)
void ewma_phase3(const nf4* __restrict__ data4,
                 const nf4* __restrict__ carry4,
                 nf4* __restrict__ out4,
                 nf4* __restrict__ out_last4,
                 const float* __restrict__ alpha_p) {
    const float alpha = alpha_p[0];
    const float decay = 1.0f - alpha;
    const int tid = threadIdx.x;
    const int c = blockIdx.x;
    const nf4 cin = carry4[c * D4 + tid];
    const nf4* p = data4 + (size_t)c * TCH * D4 + tid;
    nf4* o = out4 + (size_t)c * TCH * D4 + tid;
    float z0 = 0.f, z1 = 0.f, z2 = 0.f, z3 = 0.f, pw = 1.f;
#pragma unroll
    for (int i = 0; i < TCH; ++i) {
        nf4 x = p[(size_t)i * D4];
        z0 = fmaf(decay, z0, alpha * x.x);
        z1 = fmaf(decay, z1, alpha * x.y);
        z2 = fmaf(decay, z2, alpha * x.z);
        z3 = fmaf(decay, z3, alpha * x.w);
        pw *= decay;
        nf4 yv;
        yv.x = fmaf(pw, cin.x, z0);
        yv.y = fmaf(pw, cin.y, z1);
        yv.z = fmaf(pw, cin.z, z2);
        yv.w = fmaf(pw, cin.w, z3);
        o[(size_t)i * D4] = yv;
    }
    if (c == CCH - 1) {
        nf4 yl;
        yl.x = fmaf(pw, cin.x, z0);
        yl.y = fmaf(pw, cin.y, z1);
        yl.z = fmaf(pw, cin.z, z2);
        yl.w = fmaf(pw, cin.w, z3);
        out_last4[tid] = yl;
    }
}

extern "C" void kernel_launch(void* const* d_in, const int* in_sizes, int n_in,
                              void* d_out, int out_size, void* d_ws, size_t ws_size,
                              hipStream_t stream) {
    const float* data    = (const float*)d_in[0];
    const float* first   = (const float*)d_in[1];
    const float* alpha_p = (const float*)d_in[2];
    float* out = (float*)d_out;

    float* zend  = (float*)d_ws;              // CCH*DC floats = 8 MB
    float* carry = zend + (size_t)CCH * DC;   // CCH*DC floats = 8 MB

    ewma_phase1<<<CCH, TPB, 0, stream>>>(
        (const nf4*)data, (nf4*)zend, alpha_p);

    ewma_phase2<<<DC / (TPB / 64), TPB, 0, stream>>>(
        zend, first, carry, alpha_p);

    ewma_phase3<<<CCH, TPB, 0, stream>>>(
        (const nf4*)data, (const nf4*)carry, (nf4*)out,
        (nf4*)(out + (size_t)LT * DC), alpha_p);
}